// Round 17
// baseline (3545.763 us; speedup 1.0000x reference)
//
#include <hip/hip_runtime.h>
#include <hip/hip_bf16.h>

#define L_   12
#define B_   16
#define S_   197
#define D_   768
#define DFF_ 3072
#define NH_  12
#define HD_  64
#define NCLS_ 1000
#define MROWS (B_*S_)     // 3152
#define MPAD  3200
#define SPAD  224         // padded S (K dim for PV / vT col count)
#define BH_   (B_*NH_)    // 192
#define SP_   232         // P LDS row stride (bf16) -> 2-way bank alias (free)

typedef short s16x8 __attribute__((ext_vector_type(8)));
typedef float f32x4 __attribute__((ext_vector_type(4)));
typedef unsigned short u16x4 __attribute__((ext_vector_type(4)));

__device__ inline unsigned short f2b(float f) {
  unsigned u = __builtin_bit_cast(unsigned, f);
  u += 0x7fffu + ((u >> 16) & 1u);
  return (unsigned short)(u >> 16);
}

__device__ inline float b2f(unsigned short u) {
  return __builtin_bit_cast(float, ((unsigned)u) << 16);
}

__device__ inline f32x4 mfma16(s16x8 a, s16x8 b, f32x4 c) {
  return __builtin_amdgcn_mfma_f32_16x16x32_bf16(a, b, c, 0, 0, 0);
}

// async global->LDS, 16B per lane; LDS dest = wave-uniform base + lane*16
__device__ inline void gload16(const void* g, void* l) {
  __builtin_amdgcn_global_load_lds(
      (const __attribute__((address_space(1))) unsigned int*)g,
      (__attribute__((address_space(3))) unsigned int*)l,
      16, 0, 0);
}

// ---------------- weight fp32 -> bf16 (vectorized float4) ----------------
__global__ __launch_bounds__(256) void cvt_bf16(const float* __restrict__ in,
                                                unsigned short* __restrict__ out, long n4) {
  long i = (long)blockIdx.x * 256 + threadIdx.x;
  long stride = (long)gridDim.x * 256;
  for (; i < n4; i += stride) {
    f32x4 v = ((const f32x4*)in)[i];
    u16x4 o = { f2b(v[0]), f2b(v[1]), f2b(v[2]), f2b(v[3]) };
    ((u16x4*)out)[i] = o;
  }
}

// concat Wq|Wk|Wv per layer into [L][2304][768] bf16
__global__ __launch_bounds__(256) void cvt_qkv(const float* __restrict__ Wq,
                                               const float* __restrict__ Wk,
                                               const float* __restrict__ Wv,
                                               unsigned short* __restrict__ dst) {
  const int l = blockIdx.z, sel = blockIdx.y;
  const float* src = (sel == 0 ? Wq : (sel == 1 ? Wk : Wv)) + (size_t)l * D_ * D_;
  unsigned short* d = dst + ((size_t)l * 3 + sel) * D_ * D_;
  int i4 = blockIdx.x * 256 + threadIdx.x;   // 576*256 = D_*D_/4
  f32x4 v = ((const f32x4*)src)[i4];
  u16x4 o = { f2b(v[0]), f2b(v[1]), f2b(v[2]), f2b(v[3]) };
  ((u16x4*)d)[i4] = o;
}

__global__ __launch_bounds__(256) void cvt_bias_qkv(const float* __restrict__ bq,
                                                    const float* __restrict__ bk,
                                                    const float* __restrict__ bv,
                                                    float* __restrict__ dst) {
  int i = blockIdx.x * 256 + threadIdx.x;   // L*2304
  int l = i / 2304, r = i - l * 2304;
  int sel = r / 768, c = r - sel * 768;
  dst[i] = (sel == 0 ? bq : (sel == 1 ? bk : bv))[l * 768 + c];
}

// ---------------- im2col for patch embedding ----------------
__global__ __launch_bounds__(256) void im2col(const float* __restrict__ x,
                                              unsigned short* __restrict__ Xp) {
  int idx = blockIdx.x * 256 + threadIdx.x;
  if (idx >= 3136 * 768) return;
  int m = idx / 768, kk = idx - m * 768;
  int b = m / 196, p = m - b * 196;
  int ph = p / 14, pw = p - ph * 14;
  int c = kk >> 8, rr = kk & 255;
  int i = rr >> 4, j = rr & 15;
  float v = x[(((size_t)b * 3 + c) * 224 + ph * 16 + i) * 224 + pw * 16 + j];
  Xp[idx] = f2b(v);
}

// ---------------- init cls rows: h[b*197][d] = cls[d] + pos[d] ----------------
__global__ __launch_bounds__(256) void cls_init(float* __restrict__ h,
                                                const float* __restrict__ cls,
                                                const float* __restrict__ pos) {
  int idx = blockIdx.x * 256 + threadIdx.x;
  if (idx >= B_ * D_) return;
  int b = idx / D_, d = idx - b * D_;
  h[(size_t)(b * S_) * D_ + d] = cls[d] + pos[d];
}

// ---------------- V transpose: vbuf[b*197+s][e] -> vT[(b*768+e)*224+s], zero pad s>=197 ----
__global__ __launch_bounds__(256) void transpose_v(const unsigned short* __restrict__ vbuf,
                                                   unsigned short* __restrict__ vT) {
  __shared__ unsigned short ld[64][65];
  const int b = blockIdx.x, eb = blockIdx.y, sb = blockIdx.z;
  const int t = threadIdx.x;
  const int r = t >> 2;
  const int c4 = (t & 3) << 4;
  const int s_in = sb * 64 + r;
  if (s_in < S_) {
    const unsigned short* src = vbuf + ((size_t)(b * S_ + s_in)) * D_ + eb * 64 + c4;
    s16x8 v0 = *(const s16x8*)(src);
    s16x8 v1 = *(const s16x8*)(src + 8);
#pragma unroll
    for (int j = 0; j < 8; ++j) ld[r][c4 + j] = (unsigned short)v0[j];
#pragma unroll
    for (int j = 0; j < 8; ++j) ld[r][c4 + 8 + j] = (unsigned short)v1[j];
  }
  __syncthreads();
  const int er = t >> 2;
  const int sc0 = (t & 3) << 4;
  if (sb * 64 + sc0 >= SPAD) return;
  s16x8 o0, o1;
#pragma unroll
  for (int j = 0; j < 8; ++j) {
    int sj = sb * 64 + sc0 + j;
    o0[j] = (short)((sj < S_) ? ld[sc0 + j][er] : 0);
  }
#pragma unroll
  for (int j = 0; j < 8; ++j) {
    int sj = sb * 64 + sc0 + 8 + j;
    o1[j] = (short)((sj < S_) ? ld[sc0 + 8 + j][er] : 0);
  }
  unsigned short* dst = vT + ((size_t)(b * D_ + eb * 64 + er)) * SPAD + sb * 64 + sc0;
  *(s16x8*)dst = o0;
  *(s16x8*)(dst + 8) = o1;
}

// ---------------- GEMM: C = A(bf16)[M,K](lda) @ W(bf16)[N,K]^T ----------------
// R16 structure (best). MEASUREMENT: runtime `repeat` re-runs acc+K-loop; outputs
// are identical each rep (acc reset per rep), so numerics are unchanged.
template<int MODE, int KSPLIT>
__global__ __launch_bounds__(256, 2) void gemm_bt(const unsigned short* __restrict__ A,
                                                  const unsigned short* __restrict__ W,
                                                  const float* __restrict__ bias,
                                                  const float* __restrict__ pos,
                                                  float* __restrict__ Cf,
                                                  unsigned short* __restrict__ Cb,
                                                  unsigned short* __restrict__ Cb2,
                                                  unsigned short* __restrict__ Cb3,
                                                  int M, int N, int K, int lda,
                                                  int repeat) {
  __shared__ unsigned short As[2][128 * 32];
  __shared__ unsigned short Bs[2][64 * 32];
  const int t = threadIdx.x;
  const int lane = t & 63;
  const int w = t >> 6;
  const int wr = (w >> 1) << 6;    // 0 or 64
  const int wc = (w & 1) << 5;     // 0 or 32
  // ---- block-order swizzle (bijective XCD chunk + M-supertile, m-fast) ----
  const int gx = gridDim.x, gy = gridDim.y;
  const int nwg = gx * gy * (int)gridDim.z;
  int o = ((int)blockIdx.z * gy + (int)blockIdx.y) * gx + (int)blockIdx.x;
  int q8 = nwg >> 3, r8 = nwg & 7;
  int xcd = o & 7, i8 = o >> 3;
  int wgid = (xcd < r8 ? xcd * (q8 + 1) : r8 * (q8 + 1) + (xcd - r8) * q8) + i8;
  int z = wgid / (gx * gy);
  int rem = wgid - z * (gx * gy);
  const int SM = (gx + 1) >> 1;    // 13 for gx=25
  int m, n;
  {
    int g0sz = SM * gy;
    if (rem < g0sz) { n = rem / SM; m = rem - n * SM; }
    else {
      int r2 = rem - g0sz;
      int L2m = gx - SM;           // 12
      n = r2 / L2m; m = SM + (r2 - n * L2m);
    }
  }
  const size_t tileM = (size_t)m * 128;
  const int tileN = n * 64;
  const int kbeg = (KSPLIT > 1) ? z * (K / KSPLIT) : 0;
  const int nsteps = (K / KSPLIT) / 32;
  const int rrow = lane & 15;
  const int r0 = t >> 2;           // staging row 0..63
  // LDS XOR-swizzle: swizzled SOURCE col-unit = (t&3) ^ ((row>>1)&3) = (t>>3)&3
  const int c0s = ((t & 3) ^ ((t >> 3) & 3)) << 3;
  const unsigned short* ga0 = A + (tileM + r0) * (size_t)lda + kbeg + c0s;
  const unsigned short* ga1 = ga0 + (size_t)64 * lda;
  const unsigned short* gb0 = W + ((size_t)tileN + r0) * K + kbeg + c0s;
  auto stage = [&](int buf, int kof) {
    gload16(ga0 + kof, As[buf] + w * 512);
    gload16(ga1 + kof, As[buf] + 2048 + w * 512);
    gload16(gb0 + kof, Bs[buf] + w * 512);
  };
  // swizzled ds_read k-unit: (lane>>4) ^ ((rrow>>1)&3) — frag-row invariant
  const int uk = (((lane >> 4) ^ ((rrow >> 1) & 3)) << 3);
  f32x4 acc[4][2];
  for (int rep = 0; rep < repeat; ++rep) {
    if (rep) __syncthreads();      // WAR: prev rep's reads done before restage
#pragma unroll
    for (int mi = 0; mi < 4; ++mi)
#pragma unroll
      for (int ni = 0; ni < 2; ++ni)
        acc[mi][ni] = (f32x4){0.f, 0.f, 0.f, 0.f};
    stage(0, 0);
    __syncthreads();               // tile 0 resident
    int cur = 0;
    for (int ks = 0; ks < nsteps; ++ks) {
      if (ks + 1 < nsteps) stage(cur ^ 1, (ks + 1) * 32);
      s16x8 af[4], bfr[2];
#pragma unroll
      for (int i = 0; i < 4; ++i)
        af[i] = *(const s16x8*)(As[cur] + (wr + i * 16 + rrow) * 32 + uk);
#pragma unroll
      for (int i = 0; i < 2; ++i)
        bfr[i] = *(const s16x8*)(Bs[cur] + (wc + i * 16 + rrow) * 32 + uk);
#pragma unroll
      for (int mi = 0; mi < 4; ++mi)
#pragma unroll
        for (int ni = 0; ni < 2; ++ni)
          acc[mi][ni] = mfma16(af[mi], bfr[ni], acc[mi][ni]);
      if (ks + 1 < nsteps) { __syncthreads(); cur ^= 1; }
    }
  }
  const int rg = lane >> 4;
#pragma unroll
  for (int mi = 0; mi < 4; ++mi) {
#pragma unroll
    for (int ni = 0; ni < 2; ++ni) {
#pragma unroll
      for (int r = 0; r < 4; ++r) {
        int row = (int)tileM + wr + mi * 16 + rg * 4 + r;
        int col = tileN + wc + ni * 16 + rrow;
        if (row < M) {
          float v = acc[mi][ni][r];
          if (MODE == 2) {
            v += bias[col];
            float g = 0.5f * v * (1.0f + erff(v * 0.70710678118654752f));
            Cb[(size_t)row * N + col] = f2b(g);
          } else if (MODE == 3) {
            int bb = row / 196, pp = row - bb * 196;
            v += bias[col] + pos[(size_t)(1 + pp) * D_ + col];
            Cf[((size_t)(bb * 197 + 1 + pp)) * D_ + col] = v;
          } else if (MODE == 5) {
            v += bias[col];
            unsigned short bv = f2b(v);
            if (col < 768) {
              Cb[(size_t)row * 768 + col] = bv;
            } else if (col < 1536) {
              Cb2[(size_t)row * 768 + (col - 768)] = bv;
            } else {
              Cb3[(size_t)row * 768 + (col - 1536)] = bv;   // row-major vbuf (coalesced)
            }
          } else if (MODE == 6) {
            Cb[((size_t)z * MROWS + row) * N + col] = f2b(v);  // bf16 partial
          }
        }
      }
    }
  }
}

// ---------------- fused K-split reduce + residual + bias + LayerNorm ----------------
// VECTORIZED (R16). P is BF16 partials (NS slices).
template<int NS, bool CLS>
__global__ __launch_bounds__(256) void reduce_ln(const unsigned short* __restrict__ P,
                                                 const float* __restrict__ bias,
                                                 float* __restrict__ h,
                                                 const float* __restrict__ g,
                                                 const float* __restrict__ bb,
                                                 unsigned short* __restrict__ nbuf,
                                                 const float* __restrict__ g2,
                                                 const float* __restrict__ b2,
                                                 float* __restrict__ cls_out) {
  const int r = CLS ? blockIdx.x * S_ : blockIdx.x;
  const int t = threadIdx.x;
  float* hr = h + (size_t)r * D_;
  const int c4 = t << 2;
  float v0 = 0.f, v1 = 0.f, v2 = 0.f, v3 = 0.f;
  if (t < 192) {
    f32x4 hv = *(const f32x4*)(hr + c4);
    f32x4 bv = *(const f32x4*)(bias + c4);
    v0 = hv[0] + bv[0]; v1 = hv[1] + bv[1]; v2 = hv[2] + bv[2]; v3 = hv[3] + bv[3];
#pragma unroll
    for (int z = 0; z < NS; ++z) {
      u16x4 pv = *(const u16x4*)(P + ((size_t)z * MROWS + r) * D_ + c4);
      v0 += b2f(pv[0]); v1 += b2f(pv[1]); v2 += b2f(pv[2]); v3 += b2f(pv[3]);
    }
  }
  float s = v0 + v1 + v2 + v3;
  float s2 = v0 * v0 + v1 * v1 + v2 * v2 + v3 * v3;
  __shared__ float rs_[4], rs2_[4];
  const int lane = t & 63, w = t >> 6;
#pragma unroll
  for (int m = 32; m; m >>= 1) { s += __shfl_xor(s, m); s2 += __shfl_xor(s2, m); }
  if (lane == 0) { rs_[w] = s; rs2_[w] = s2; }
  __syncthreads();
  s = rs_[0] + rs_[1] + rs_[2] + rs_[3];
  s2 = rs2_[0] + rs2_[1] + rs2_[2] + rs2_[3];
  const float mu = s * (1.0f / 768.0f);
  const float var = s2 * (1.0f / 768.0f) - mu * mu;
  const float rstd = rsqrtf(var + 1e-6f);
  if (t >= 192) return;
  if (!CLS) {
    f32x4 ho = { v0, v1, v2, v3 };
    *(f32x4*)(hr + c4) = ho;
    f32x4 gv = *(const f32x4*)(g + c4);
    f32x4 bbv = *(const f32x4*)(bb + c4);
    u16x4 no = { f2b((v0 - mu) * rstd * gv[0] + bbv[0]),
                 f2b((v1 - mu) * rstd * gv[1] + bbv[1]),
                 f2b((v2 - mu) * rstd * gv[2] + bbv[2]),
                 f2b((v3 - mu) * rstd * gv[3] + bbv[3]) };
    *(u16x4*)(nbuf + (size_t)r * D_ + c4) = no;
  } else {
    f32x4 gv = *(const f32x4*)(g2 + c4);
    f32x4 bbv = *(const f32x4*)(b2 + c4);
    f32x4 oo = { (v0 - mu) * rstd * gv[0] + bbv[0],
                 (v1 - mu) * rstd * gv[1] + bbv[1],
                 (v2 - mu) * rstd * gv[2] + bbv[2],
                 (v3 - mu) * rstd * gv[3] + bbv[3] };
    *(f32x4*)(cls_out + (size_t)blockIdx.x * D_ + c4) = oo;
  }
}

// ---------------- initial layernorm (fp32 in -> bf16 out) ----------------
__global__ __launch_bounds__(256) void ln_rows_bf16(const float* __restrict__ x,
                                                    const float* __restrict__ g,
                                                    const float* __restrict__ bb,
                                                    unsigned short* __restrict__ out) {
  const int row = blockIdx.x;
  const float* xr = x + (size_t)row * D_;
  const int t = threadIdx.x;
  float v0 = xr[t], v1 = xr[t + 256], v2 = xr[t + 512];
  float s = v0 + v1 + v2;
  float s2 = v0 * v0 + v1 * v1 + v2 * v2;
  __shared__ float rs_[4], rs2_[4];
  const int lane = t & 63, w = t >> 6;
#pragma unroll
  for (int m = 32; m; m >>= 1) { s += __shfl_xor(s, m); s2 += __shfl_xor(s2, m); }
  if (lane == 0) { rs_[w] = s; rs2_[w] = s2; }
  __syncthreads();
  s = rs_[0] + rs_[1] + rs_[2] + rs_[3];
  s2 = rs2_[0] + rs2_[1] + rs2_[2] + rs2_[3];
  const float mu = s * (1.0f / 768.0f);
  const float var = s2 * (1.0f / 768.0f) - mu * mu;
  const float rstd = rsqrtf(var + 1e-6f);
  unsigned short* o = out + (size_t)row * D_;
  o[t]       = f2b((v0 - mu) * rstd * g[t]       + bb[t]);
  o[t + 256] = f2b((v1 - mu) * rstd * g[t + 256] + bb[t + 256]);
  o[t + 512] = f2b((v2 - mu) * rstd * g[t + 512] + bb[t + 512]);
}

// ---------------- fused attention (repeat-instrumented, idempotent) ----------------
__global__ __launch_bounds__(64) void attn_fused(const unsigned short* __restrict__ q,
                                                 const unsigned short* __restrict__ k,
                                                 const unsigned short* __restrict__ vT,
                                                 float* __restrict__ sout,
                                                 unsigned short* __restrict__ attn,
                                                 int repeat) {
  __shared__ unsigned short sP[16 * SP_];
  const int bh = blockIdx.x;
  const int b = bh / NH_, h = bh % NH_;
  const int strip = blockIdx.y;
  const int lane = threadIdx.x;
  const int rrow = lane & 15;
  const int kk8 = (lane >> 4) << 3;
  const int rg = lane >> 4;
  const unsigned short* qb = q + ((size_t)b * S_) * D_ + h * HD_;
  const unsigned short* kb = k + ((size_t)b * S_) * D_ + h * HD_;
  for (int rep = 0; rep < repeat; ++rep) {
    f32x4 acc[13] = {};
#pragma unroll
    for (int ks = 0; ks < 2; ++ks) {
      s16x8 af = *(const s16x8*)(qb + (size_t)(strip * 16 + rrow) * D_ + ks * 32 + kk8);
#pragma unroll
      for (int nf = 0; nf < 13; ++nf) {
        s16x8 bfr = *(const s16x8*)(kb + (size_t)(nf * 16 + rrow) * D_ + ks * 32 + kk8);
        acc[nf] = mfma16(af, bfr, acc[nf]);
      }
    }
#pragma unroll
    for (int r = 0; r < 4; ++r) {
      const int lr = rg * 4 + r;
      const int row = strip * 16 + lr;
      float mx = -1e30f;
#pragma unroll
      for (int nf = 0; nf < 13; ++nf) {
        int col = nf * 16 + rrow;
        float v = acc[nf][r] * 0.125f;
        if (col < S_) mx = fmaxf(mx, v);
      }
#pragma unroll
      for (int m = 1; m < 16; m <<= 1) mx = fmaxf(mx, __shfl_xor(mx, m));
      float e[13], sum = 0.f;
#pragma unroll
      for (int nf = 0; nf < 13; ++nf) {
        int col = nf * 16 + rrow;
        e[nf] = (col < S_) ? expf(acc[nf][r] * 0.125f - mx) : 0.f;
        sum += e[nf];
      }
#pragma unroll
      for (int m = 1; m < 16; m <<= 1) sum += __shfl_xor(sum, m);
      const float inv = 1.0f / sum;
      float* so = sout + ((size_t)bh * S_ + row) * S_;
#pragma unroll
      for (int nf = 0; nf < 13; ++nf) {
        int col = nf * 16 + rrow;
        float p = e[nf] * inv;
        if (row < S_ && col < S_) so[col] = p;
        sP[lr * SP_ + col] = f2b((col < S_) ? p : 0.f);
      }
    }
#pragma unroll
    for (int j = 0; j < 6; ++j) {
      int idx = lane + j * 64;
      int pr = idx / 24, pc = idx - pr * 24;
      sP[pr * SP_ + 208 + pc] = 0;
    }
    const unsigned short* Vb = vT + ((size_t)b * D_ + h * HD_) * SPAD;
    f32x4 oacc[4] = {};
#pragma unroll
    for (int ks = 0; ks < 7; ++ks) {
      s16x8 af = *(const s16x8*)(sP + rrow * SP_ + ks * 32 + kk8);
#pragma unroll
      for (int nf = 0; nf < 4; ++nf) {
        s16x8 bfr = *(const s16x8*)(Vb + (size_t)(nf * 16 + rrow) * SPAD + ks * 32 + kk8);
        oacc[nf] = mfma16(af, bfr, oacc[nf]);
      }
    }
#pragma unroll
    for (int r = 0; r < 4; ++r) {
      int row = strip * 16 + rg * 4 + r;
      if (row < S_) {
#pragma unroll
        for (int nf = 0; nf < 4; ++nf) {
          int col = h * HD_ + nf * 16 + rrow;
          attn[(size_t)(b * S_ + row) * D_ + col] = f2b(oacc[nf][r]);
        }
      }
    }
  }
}

// ---------------- classification head ----------------
__global__ __launch_bounds__(256) void head_kernel(const float* __restrict__ cls_ln,
                                                   const float* __restrict__ Wh,
                                                   const float* __restrict__ bh_,
                                                   float* __restrict__ out) {
  int gw = (blockIdx.x * 256 + threadIdx.x) >> 6;
  int lane = threadIdx.x & 63;
  if (gw >= B_ * NCLS_) return;
  int b = gw / NCLS_, c = gw - b * NCLS_;
  const float* x = cls_ln + (size_t)b * D_;
  const float* wr = Wh + (size_t)c * D_;
  float s = 0.f;
  for (int d = lane; d < D_; d += 64) s += x[d] * wr[d];
#pragma unroll
  for (int m = 32; m; m >>= 1) s += __shfl_xor(s, m);
  if (lane == 0) out[(size_t)b * NCLS_ + c] = s + bh_[c];
}

extern "C" void kernel_launch(void* const* d_in, const int* in_sizes, int n_in,
                              void* d_out, int out_size, void* d_ws, size_t ws_size,
                              hipStream_t stream) {
  const float* x     = (const float*)d_in[0];
  const float* Wconv = (const float*)d_in[1];
  const float* bconv = (const float*)d_in[2];
  const float* cls_e = (const float*)d_in[3];
  const float* pos_e = (const float*)d_in[4];
  const float* Wq    = (const float*)d_in[5];
  const float* bq    = (const float*)d_in[6];
  const float* Wk    = (const float*)d_in[7];
  const float* bk    = (const float*)d_in[8];
  const float* Wv    = (const float*)d_in[9];
  const float* bv    = (const float*)d_in[10];
  const float* Wo    = (const float*)d_in[11];
  const float* bo    = (const float*)d_in[12];
  const float* ln1g  = (const float*)d_in[13];
  const float* ln1b  = (const float*)d_in[14];
  const float* Wff1  = (const float*)d_in[15];
  const float* bff1  = (const float*)d_in[16];
  const float* Wff2  = (const float*)d_in[17];
  const float* bff2  = (const float*)d_in[18];
  const float* ln2g  = (const float*)d_in[19];
  const float* ln2b  = (const float*)d_in[20];
  const float* lnfg  = (const float*)d_in[21];
  const float* lnfb  = (const float*)d_in[22];
  const float* Whead = (const float*)d_in[23];
  const float* bhead = (const float*)d_in[24];

  char* base = (char*)d_ws;
  size_t off = 0;
  auto alloc = [&](size_t bytes) {
    void* p = base + off;
    off = (off + bytes + 255) & ~(size_t)255;
    return p;
  };
  unsigned short* Wqkv_b = (unsigned short*)alloc((size_t)L_ * 3 * D_ * D_ * 2);
  unsigned short* Wo_b   = (unsigned short*)alloc((size_t)L_ * D_ * D_ * 2);
  unsigned short* Wff1_b = (unsigned short*)alloc((size_t)L_ * DFF_ * D_ * 2);
  unsigned short* Wff2_b = (unsigned short*)alloc((size_t)L_ * D_ * DFF_ * 2);
  unsigned short* Wconv_b= (unsigned short*)alloc((size_t)D_ * D_ * 2);
  float*          bqkv   = (float*)alloc((size_t)L_ * 2304 * 4);
  float*          h      = (float*)alloc((size_t)MPAD * D_ * 4);
  unsigned short* nbuf   = (unsigned short*)alloc((size_t)MPAD * D_ * 2);
  unsigned short* qbuf   = (unsigned short*)alloc((size_t)MPAD * D_ * 2);
  unsigned short* kbuf   = (unsigned short*)alloc((size_t)MPAD * D_ * 2);
  unsigned short* vbuf   = (unsigned short*)alloc((size_t)MPAD * D_ * 2);
  unsigned short* vT     = (unsigned short*)alloc((size_t)B_ * D_ * SPAD * 2);
  unsigned short* attn   = (unsigned short*)alloc((size_t)MPAD * D_ * 2);
  unsigned short* ff     = (unsigned short*)alloc((size_t)MPAD * DFF_ * 2);
  unsigned short* Xp     = (unsigned short*)alloc((size_t)MPAD * D_ * 2);
  unsigned short* Po     = (unsigned short*)alloc((size_t)2 * MROWS * D_ * 2);
  unsigned short* Pf     = (unsigned short*)alloc((size_t)4 * MROWS * D_ * 2);
  float*          cls_ln = (float*)alloc((size_t)B_ * D_ * 4);
  (void)ws_size; (void)in_sizes; (void)n_in; (void)out_size;

  float* out_f = (float*)d_out;
  float* scores_base = out_f + (size_t)B_ * NCLS_;

  // weight conversions
  cvt_qkv<<<dim3(576, 3, L_), 256, 0, stream>>>(Wq, Wk, Wv, Wqkv_b);
  cvt_bf16<<<2048, 256, 0, stream>>>(Wo,   Wo_b,   (long)L_ * D_ * D_ / 4);
  cvt_bf16<<<2048, 256, 0, stream>>>(Wff1, Wff1_b, (long)L_ * DFF_ * D_ / 4);
  cvt_bf16<<<2048, 256, 0, stream>>>(Wff2, Wff2_b, (long)L_ * D_ * DFF_ / 4);
  cvt_bf16<<<576, 256, 0, stream>>>(Wconv, Wconv_b, (long)D_ * D_ / 4);
  cvt_bias_qkv<<<(L_ * 2304) / 256, 256, 0, stream>>>(bq, bk, bv, bqkv);

  // patch embed (pos folded into epilogue) + cls row init
  im2col<<<(3136 * 768) / 256, 256, 0, stream>>>(x, Xp);
  gemm_bt<3, 1><<<dim3(25, 12), 256, 0, stream>>>(Xp, Wconv_b, bconv, pos_e, h,
                                                  nullptr, nullptr, nullptr, 3136, D_, D_, D_, 1);
  cls_init<<<(B_ * D_ + 255) / 256, 256, 0, stream>>>(h, cls_e, pos_e);
  ln_rows_bf16<<<MROWS, 256, 0, stream>>>(h, ln1g, ln1b, nbuf);

  for (int l = 0; l < L_; ++l) {
    const unsigned short* wqkv = Wqkv_b + (size_t)l * 3 * D_ * D_;
    const unsigned short* wo = Wo_b + (size_t)l * D_ * D_;
    const unsigned short* w1 = Wff1_b + (size_t)l * DFF_ * D_;
    const unsigned short* w2 = Wff2_b + (size_t)l * D_ * DFF_;
    float* sc = scores_base + (size_t)l * BH_ * S_ * S_;
    // MEASUREMENT: layer 0's 5 idempotent heavy kernels run 16x to surface
    // post-L2-fix per-kernel counters in rocprof top-5. Other layers: 1x.
    const int rep = (l == 0) ? 16 : 1;

    gemm_bt<5, 1><<<dim3(25, 36), 256, 0, stream>>>(nbuf, wqkv, bqkv + l * 2304, nullptr,
                                                    nullptr, qbuf, kbuf, vbuf, MROWS, 2304, D_, D_,
                                                    rep);
    transpose_v<<<dim3(B_, 12, 4), 256, 0, stream>>>(vbuf, vT);
    attn_fused<<<dim3(BH_, 13), 64, 0, stream>>>(qbuf, kbuf, vT, sc, attn, rep);
    gemm_bt<6, 2><<<dim3(25, 12, 2), 256, 0, stream>>>(attn, wo, nullptr, nullptr, nullptr,
                                                       Po, nullptr, nullptr, MROWS, D_, D_, D_,
                                                       rep);
    reduce_ln<2, false><<<MROWS, 256, 0, stream>>>(Po, bo + l * D_, h,
                                                   ln2g + l * D_, ln2b + l * D_, nbuf,
                                                   nullptr, nullptr, nullptr);
    gemm_bt<2, 1><<<dim3(25, 48), 256, 0, stream>>>(nbuf, w1, bff1 + l * DFF_, nullptr,
                                                    nullptr, ff, nullptr, nullptr, MROWS, DFF_, D_, D_,
                                                    rep);
    gemm_bt<6, 4><<<dim3(25, 12, 4), 256, 0, stream>>>(ff, w2, nullptr, nullptr, nullptr,
                                                       Pf, nullptr, nullptr, MROWS, D_, DFF_, DFF_,
                                                       rep);
    if (l < L_ - 1) {
      reduce_ln<4, false><<<MROWS, 256, 0, stream>>>(Pf, bff2 + l * D_, h,
                                                     ln1g + (l + 1) * D_, ln1b + (l + 1) * D_, nbuf,
                                                     nullptr, nullptr, nullptr);
    } else {
      reduce_ln<4, true><<<B_, 256, 0, stream>>>(Pf, bff2 + l * D_, h,
                                                 nullptr, nullptr, nullptr,
                                                 lnfg, lnfb, cls_ln);
    }
  }

  head_kernel<<<(B_ * NCLS_ * 64) / 256, 256, 0, stream>>>(cls_ln, Whead, bhead, out_f);
}

// Round 18
// 2071.737 us; speedup vs baseline: 1.7115x; 1.7115x over previous
//
#include <hip/hip_runtime.h>
#include <hip/hip_bf16.h>

#define L_   12
#define B_   16
#define S_   197
#define D_   768
#define DFF_ 3072
#define NH_  12
#define HD_  64
#define NCLS_ 1000
#define MROWS (B_*S_)     // 3152
#define MPAD  3200
#define SPAD  224         // padded S (K dim for PV / vT col count)
#define BH_   (B_*NH_)    // 192
#define SP_   232         // P LDS row stride (bf16) -> 2-way bank alias (free)

typedef short s16x8 __attribute__((ext_vector_type(8)));
typedef float f32x4 __attribute__((ext_vector_type(4)));
typedef unsigned short u16x4 __attribute__((ext_vector_type(4)));

__device__ inline unsigned short f2b(float f) {
  unsigned u = __builtin_bit_cast(unsigned, f);
  u += 0x7fffu + ((u >> 16) & 1u);
  return (unsigned short)(u >> 16);
}

__device__ inline float b2f(unsigned short u) {
  return __builtin_bit_cast(float, ((unsigned)u) << 16);
}

__device__ inline f32x4 mfma16(s16x8 a, s16x8 b, f32x4 c) {
  return __builtin_amdgcn_mfma_f32_16x16x32_bf16(a, b, c, 0, 0, 0);
}

// async global->LDS, 16B per lane; LDS dest = wave-uniform base + lane*16
__device__ inline void gload16(const void* g, void* l) {
  __builtin_amdgcn_global_load_lds(
      (const __attribute__((address_space(1))) unsigned int*)g,
      (__attribute__((address_space(3))) unsigned int*)l,
      16, 0, 0);
}

// ---------------- weight fp32 -> bf16 (vectorized float4) ----------------
__global__ __launch_bounds__(256) void cvt_bf16(const float* __restrict__ in,
                                                unsigned short* __restrict__ out, long n4) {
  long i = (long)blockIdx.x * 256 + threadIdx.x;
  long stride = (long)gridDim.x * 256;
  for (; i < n4; i += stride) {
    f32x4 v = ((const f32x4*)in)[i];
    u16x4 o = { f2b(v[0]), f2b(v[1]), f2b(v[2]), f2b(v[3]) };
    ((u16x4*)out)[i] = o;
  }
}

// concat Wq|Wk|Wv per layer into [L][2304][768] bf16
__global__ __launch_bounds__(256) void cvt_qkv(const float* __restrict__ Wq,
                                               const float* __restrict__ Wk,
                                               const float* __restrict__ Wv,
                                               unsigned short* __restrict__ dst) {
  const int l = blockIdx.z, sel = blockIdx.y;
  const float* src = (sel == 0 ? Wq : (sel == 1 ? Wk : Wv)) + (size_t)l * D_ * D_;
  unsigned short* d = dst + ((size_t)l * 3 + sel) * D_ * D_;
  int i4 = blockIdx.x * 256 + threadIdx.x;   // 576*256 = D_*D_/4
  f32x4 v = ((const f32x4*)src)[i4];
  u16x4 o = { f2b(v[0]), f2b(v[1]), f2b(v[2]), f2b(v[3]) };
  ((u16x4*)d)[i4] = o;
}

__global__ __launch_bounds__(256) void cvt_bias_qkv(const float* __restrict__ bq,
                                                    const float* __restrict__ bk,
                                                    const float* __restrict__ bv,
                                                    float* __restrict__ dst) {
  int i = blockIdx.x * 256 + threadIdx.x;   // L*2304
  int l = i / 2304, r = i - l * 2304;
  int sel = r / 768, c = r - sel * 768;
  dst[i] = (sel == 0 ? bq : (sel == 1 ? bk : bv))[l * 768 + c];
}

// ---------------- im2col for patch embedding ----------------
__global__ __launch_bounds__(256) void im2col(const float* __restrict__ x,
                                              unsigned short* __restrict__ Xp) {
  int idx = blockIdx.x * 256 + threadIdx.x;
  if (idx >= 3136 * 768) return;
  int m = idx / 768, kk = idx - m * 768;
  int b = m / 196, p = m - b * 196;
  int ph = p / 14, pw = p - ph * 14;
  int c = kk >> 8, rr = kk & 255;
  int i = rr >> 4, j = rr & 15;
  float v = x[(((size_t)b * 3 + c) * 224 + ph * 16 + i) * 224 + pw * 16 + j];
  Xp[idx] = f2b(v);
}

// ---------------- init cls rows: h[b*197][d] = cls[d] + pos[d] ----------------
__global__ __launch_bounds__(256) void cls_init(float* __restrict__ h,
                                                const float* __restrict__ cls,
                                                const float* __restrict__ pos) {
  int idx = blockIdx.x * 256 + threadIdx.x;
  if (idx >= B_ * D_) return;
  int b = idx / D_, d = idx - b * D_;
  h[(size_t)(b * S_) * D_ + d] = cls[d] + pos[d];
}

// ---------------- V transpose: vbuf[b*197+s][e] -> vT[(b*768+e)*224+s], zero pad s>=197 ----
__global__ __launch_bounds__(256) void transpose_v(const unsigned short* __restrict__ vbuf,
                                                   unsigned short* __restrict__ vT) {
  __shared__ unsigned short ld[64][65];
  const int b = blockIdx.x, eb = blockIdx.y, sb = blockIdx.z;
  const int t = threadIdx.x;
  const int r = t >> 2;
  const int c4 = (t & 3) << 4;
  const int s_in = sb * 64 + r;
  if (s_in < S_) {
    const unsigned short* src = vbuf + ((size_t)(b * S_ + s_in)) * D_ + eb * 64 + c4;
    s16x8 v0 = *(const s16x8*)(src);
    s16x8 v1 = *(const s16x8*)(src + 8);
#pragma unroll
    for (int j = 0; j < 8; ++j) ld[r][c4 + j] = (unsigned short)v0[j];
#pragma unroll
    for (int j = 0; j < 8; ++j) ld[r][c4 + 8 + j] = (unsigned short)v1[j];
  }
  __syncthreads();
  const int er = t >> 2;
  const int sc0 = (t & 3) << 4;
  if (sb * 64 + sc0 >= SPAD) return;
  s16x8 o0, o1;
#pragma unroll
  for (int j = 0; j < 8; ++j) {
    int sj = sb * 64 + sc0 + j;
    o0[j] = (short)((sj < S_) ? ld[sc0 + j][er] : 0);
  }
#pragma unroll
  for (int j = 0; j < 8; ++j) {
    int sj = sb * 64 + sc0 + 8 + j;
    o1[j] = (short)((sj < S_) ? ld[sc0 + 8 + j][er] : 0);
  }
  unsigned short* dst = vT + ((size_t)(b * D_ + eb * 64 + er)) * SPAD + sb * 64 + sc0;
  *(s16x8*)dst = o0;
  *(s16x8*)(dst + 8) = o1;
}

// ---------------- GEMM: C = A(bf16)[M,K](lda) @ W(bf16)[N,K]^T ----------------
// 128x64 tile, BK=32, 2-phase dbuf, global_load_lds width-16, LDS XOR-swizzle,
// L2-locality block-order swizzle (m204 XCD chunking + 13/12 M-supertile, m-fast).
// Best measured across 8 K-loop/tile/schedule variants (R4-R15).
// MODE 2: Cb = bf16(gelu(v+bias)); MODE 3: embed; MODE 5: QKV fused;
// MODE 6: K-split partials -> BF16.
template<int MODE, int KSPLIT>
__global__ __launch_bounds__(256, 2) void gemm_bt(const unsigned short* __restrict__ A,
                                                  const unsigned short* __restrict__ W,
                                                  const float* __restrict__ bias,
                                                  const float* __restrict__ pos,
                                                  float* __restrict__ Cf,
                                                  unsigned short* __restrict__ Cb,
                                                  unsigned short* __restrict__ Cb2,
                                                  unsigned short* __restrict__ Cb3,
                                                  int M, int N, int K, int lda) {
  __shared__ unsigned short As[2][128 * 32];
  __shared__ unsigned short Bs[2][64 * 32];
  const int t = threadIdx.x;
  const int lane = t & 63;
  const int w = t >> 6;
  const int wr = (w >> 1) << 6;    // 0 or 64
  const int wc = (w & 1) << 5;     // 0 or 32
  // ---- block-order swizzle (bijective XCD chunk + M-supertile, m-fast) ----
  const int gx = gridDim.x, gy = gridDim.y;
  const int nwg = gx * gy * (int)gridDim.z;
  int o = ((int)blockIdx.z * gy + (int)blockIdx.y) * gx + (int)blockIdx.x;
  int q8 = nwg >> 3, r8 = nwg & 7;
  int xcd = o & 7, i8 = o >> 3;
  int wgid = (xcd < r8 ? xcd * (q8 + 1) : r8 * (q8 + 1) + (xcd - r8) * q8) + i8;
  int z = wgid / (gx * gy);
  int rem = wgid - z * (gx * gy);
  const int SM = (gx + 1) >> 1;    // 13 for gx=25
  int m, n;
  {
    int g0sz = SM * gy;
    if (rem < g0sz) { n = rem / SM; m = rem - n * SM; }
    else {
      int r2 = rem - g0sz;
      int L2m = gx - SM;           // 12
      n = r2 / L2m; m = SM + (r2 - n * L2m);
    }
  }
  const size_t tileM = (size_t)m * 128;
  const int tileN = n * 64;
  const int kbeg = (KSPLIT > 1) ? z * (K / KSPLIT) : 0;
  const int nsteps = (K / KSPLIT) / 32;
  const int rrow = lane & 15;
  const int r0 = t >> 2;           // staging row 0..63
  // LDS XOR-swizzle: swizzled SOURCE col-unit = (t&3) ^ ((row>>1)&3) = (t>>3)&3
  const int c0s = ((t & 3) ^ ((t >> 3) & 3)) << 3;
  const unsigned short* ga0 = A + (tileM + r0) * (size_t)lda + kbeg + c0s;
  const unsigned short* ga1 = ga0 + (size_t)64 * lda;
  const unsigned short* gb0 = W + ((size_t)tileN + r0) * K + kbeg + c0s;
  auto stage = [&](int buf, int kof) {
    gload16(ga0 + kof, As[buf] + w * 512);
    gload16(ga1 + kof, As[buf] + 2048 + w * 512);
    gload16(gb0 + kof, Bs[buf] + w * 512);
  };
  // swizzled ds_read k-unit: (lane>>4) ^ ((rrow>>1)&3) — frag-row invariant
  const int uk = (((lane >> 4) ^ ((rrow >> 1) & 3)) << 3);
  f32x4 acc[4][2] = {};
  stage(0, 0);
  __syncthreads();                 // tile 0 resident
  int cur = 0;
  for (int ks = 0; ks < nsteps; ++ks) {
    if (ks + 1 < nsteps) stage(cur ^ 1, (ks + 1) * 32);  // prefetch next tile
    s16x8 af[4], bfr[2];
#pragma unroll
    for (int i = 0; i < 4; ++i)
      af[i] = *(const s16x8*)(As[cur] + (wr + i * 16 + rrow) * 32 + uk);
#pragma unroll
    for (int i = 0; i < 2; ++i)
      bfr[i] = *(const s16x8*)(Bs[cur] + (wc + i * 16 + rrow) * 32 + uk);
#pragma unroll
    for (int mi = 0; mi < 4; ++mi)
#pragma unroll
      for (int ni = 0; ni < 2; ++ni)
        acc[mi][ni] = mfma16(af[mi], bfr[ni], acc[mi][ni]);
    if (ks + 1 < nsteps) { __syncthreads(); cur ^= 1; }  // next tile resident
  }
  const int rg = lane >> 4;
#pragma unroll
  for (int mi = 0; mi < 4; ++mi) {
#pragma unroll
    for (int ni = 0; ni < 2; ++ni) {
#pragma unroll
      for (int r = 0; r < 4; ++r) {
        int row = (int)tileM + wr + mi * 16 + rg * 4 + r;
        int col = tileN + wc + ni * 16 + rrow;
        if (row < M) {
          float v = acc[mi][ni][r];
          if (MODE == 2) {
            v += bias[col];
            float g = 0.5f * v * (1.0f + erff(v * 0.70710678118654752f));
            Cb[(size_t)row * N + col] = f2b(g);
          } else if (MODE == 3) {
            int bb = row / 196, pp = row - bb * 196;
            v += bias[col] + pos[(size_t)(1 + pp) * D_ + col];
            Cf[((size_t)(bb * 197 + 1 + pp)) * D_ + col] = v;
          } else if (MODE == 5) {
            v += bias[col];
            unsigned short bv = f2b(v);
            if (col < 768) {
              Cb[(size_t)row * 768 + col] = bv;
            } else if (col < 1536) {
              Cb2[(size_t)row * 768 + (col - 768)] = bv;
            } else {
              Cb3[(size_t)row * 768 + (col - 1536)] = bv;   // row-major vbuf (coalesced)
            }
          } else if (MODE == 6) {
            Cb[((size_t)z * MROWS + row) * N + col] = f2b(v);  // bf16 partial
          }
        }
      }
    }
  }
}

// ---------------- fused K-split reduce + residual + bias + LayerNorm ----------------
// VECTORIZED: 192 active lanes x {f32x4 h/bias/g/b, u16x4 partials/nbuf}.
// P is BF16 partials (NS slices). h_new = h + sum_z P[z] + bias; writes h;
// LN(h_new)*g+b -> nbuf (bf16). CLS variant: grid = B_ blocks, final-LN only.
template<int NS, bool CLS>
__global__ __launch_bounds__(256) void reduce_ln(const unsigned short* __restrict__ P,
                                                 const float* __restrict__ bias,
                                                 float* __restrict__ h,
                                                 const float* __restrict__ g,
                                                 const float* __restrict__ bb,
                                                 unsigned short* __restrict__ nbuf,
                                                 const float* __restrict__ g2,
                                                 const float* __restrict__ b2,
                                                 float* __restrict__ cls_out) {
  const int r = CLS ? blockIdx.x * S_ : blockIdx.x;
  const int t = threadIdx.x;
  float* hr = h + (size_t)r * D_;
  const int c4 = t << 2;
  float v0 = 0.f, v1 = 0.f, v2 = 0.f, v3 = 0.f;
  if (t < 192) {
    f32x4 hv = *(const f32x4*)(hr + c4);
    f32x4 bv = *(const f32x4*)(bias + c4);
    v0 = hv[0] + bv[0]; v1 = hv[1] + bv[1]; v2 = hv[2] + bv[2]; v3 = hv[3] + bv[3];
#pragma unroll
    for (int z = 0; z < NS; ++z) {
      u16x4 pv = *(const u16x4*)(P + ((size_t)z * MROWS + r) * D_ + c4);
      v0 += b2f(pv[0]); v1 += b2f(pv[1]); v2 += b2f(pv[2]); v3 += b2f(pv[3]);
    }
  }
  float s = v0 + v1 + v2 + v3;
  float s2 = v0 * v0 + v1 * v1 + v2 * v2 + v3 * v3;
  __shared__ float rs_[4], rs2_[4];
  const int lane = t & 63, w = t >> 6;
#pragma unroll
  for (int m = 32; m; m >>= 1) { s += __shfl_xor(s, m); s2 += __shfl_xor(s2, m); }
  if (lane == 0) { rs_[w] = s; rs2_[w] = s2; }
  __syncthreads();
  s = rs_[0] + rs_[1] + rs_[2] + rs_[3];
  s2 = rs2_[0] + rs2_[1] + rs2_[2] + rs2_[3];
  const float mu = s * (1.0f / 768.0f);
  const float var = s2 * (1.0f / 768.0f) - mu * mu;
  const float rstd = rsqrtf(var + 1e-6f);
  if (t >= 192) return;
  if (!CLS) {
    f32x4 ho = { v0, v1, v2, v3 };
    *(f32x4*)(hr + c4) = ho;
    f32x4 gv = *(const f32x4*)(g + c4);
    f32x4 bbv = *(const f32x4*)(bb + c4);
    u16x4 no = { f2b((v0 - mu) * rstd * gv[0] + bbv[0]),
                 f2b((v1 - mu) * rstd * gv[1] + bbv[1]),
                 f2b((v2 - mu) * rstd * gv[2] + bbv[2]),
                 f2b((v3 - mu) * rstd * gv[3] + bbv[3]) };
    *(u16x4*)(nbuf + (size_t)r * D_ + c4) = no;
  } else {
    f32x4 gv = *(const f32x4*)(g2 + c4);
    f32x4 bbv = *(const f32x4*)(b2 + c4);
    f32x4 oo = { (v0 - mu) * rstd * gv[0] + bbv[0],
                 (v1 - mu) * rstd * gv[1] + bbv[1],
                 (v2 - mu) * rstd * gv[2] + bbv[2],
                 (v3 - mu) * rstd * gv[3] + bbv[3] };
    *(f32x4*)(cls_out + (size_t)blockIdx.x * D_ + c4) = oo;
  }
}

// ---------------- initial layernorm (fp32 in -> bf16 out) ----------------
__global__ __launch_bounds__(256) void ln_rows_bf16(const float* __restrict__ x,
                                                    const float* __restrict__ g,
                                                    const float* __restrict__ bb,
                                                    unsigned short* __restrict__ out) {
  const int row = blockIdx.x;
  const float* xr = x + (size_t)row * D_;
  const int t = threadIdx.x;
  float v0 = xr[t], v1 = xr[t + 256], v2 = xr[t + 512];
  float s = v0 + v1 + v2;
  float s2 = v0 * v0 + v1 * v1 + v2 * v2;
  __shared__ float rs_[4], rs2_[4];
  const int lane = t & 63, w = t >> 6;
#pragma unroll
  for (int m = 32; m; m >>= 1) { s += __shfl_xor(s, m); s2 += __shfl_xor(s2, m); }
  if (lane == 0) { rs_[w] = s; rs2_[w] = s2; }
  __syncthreads();
  s = rs_[0] + rs_[1] + rs_[2] + rs_[3];
  s2 = rs2_[0] + rs2_[1] + rs2_[2] + rs2_[3];
  const float mu = s * (1.0f / 768.0f);
  const float var = s2 * (1.0f / 768.0f) - mu * mu;
  const float rstd = rsqrtf(var + 1e-6f);
  unsigned short* o = out + (size_t)row * D_;
  o[t]       = f2b((v0 - mu) * rstd * g[t]       + bb[t]);
  o[t + 256] = f2b((v1 - mu) * rstd * g[t + 256] + bb[t + 256]);
  o[t + 512] = f2b((v2 - mu) * rstd * g[t + 512] + bb[t + 512]);
}

// ---------------- fused attention: QK^T -> softmax -> scores(out) + P(LDS) -> PV ----------------
__global__ __launch_bounds__(64) void attn_fused(const unsigned short* __restrict__ q,
                                                 const unsigned short* __restrict__ k,
                                                 const unsigned short* __restrict__ vT,
                                                 float* __restrict__ sout,
                                                 unsigned short* __restrict__ attn) {
  __shared__ unsigned short sP[16 * SP_];
  const int bh = blockIdx.x;
  const int b = bh / NH_, h = bh % NH_;
  const int strip = blockIdx.y;
  const int lane = threadIdx.x;
  const int rrow = lane & 15;
  const int kk8 = (lane >> 4) << 3;
  const int rg = lane >> 4;
  const unsigned short* qb = q + ((size_t)b * S_) * D_ + h * HD_;
  const unsigned short* kb = k + ((size_t)b * S_) * D_ + h * HD_;
  f32x4 acc[13] = {};
#pragma unroll
  for (int ks = 0; ks < 2; ++ks) {
    s16x8 af = *(const s16x8*)(qb + (size_t)(strip * 16 + rrow) * D_ + ks * 32 + kk8);
#pragma unroll
    for (int nf = 0; nf < 13; ++nf) {
      s16x8 bfr = *(const s16x8*)(kb + (size_t)(nf * 16 + rrow) * D_ + ks * 32 + kk8);
      acc[nf] = mfma16(af, bfr, acc[nf]);
    }
  }
#pragma unroll
  for (int r = 0; r < 4; ++r) {
    const int lr = rg * 4 + r;
    const int row = strip * 16 + lr;
    float mx = -1e30f;
#pragma unroll
    for (int nf = 0; nf < 13; ++nf) {
      int col = nf * 16 + rrow;
      float v = acc[nf][r] * 0.125f;
      if (col < S_) mx = fmaxf(mx, v);
    }
#pragma unroll
    for (int m = 1; m < 16; m <<= 1) mx = fmaxf(mx, __shfl_xor(mx, m));
    float e[13], sum = 0.f;
#pragma unroll
    for (int nf = 0; nf < 13; ++nf) {
      int col = nf * 16 + rrow;
      e[nf] = (col < S_) ? expf(acc[nf][r] * 0.125f - mx) : 0.f;
      sum += e[nf];
    }
#pragma unroll
    for (int m = 1; m < 16; m <<= 1) sum += __shfl_xor(sum, m);
    const float inv = 1.0f / sum;
    float* so = sout + ((size_t)bh * S_ + row) * S_;
#pragma unroll
    for (int nf = 0; nf < 13; ++nf) {
      int col = nf * 16 + rrow;
      float p = e[nf] * inv;
      if (row < S_ && col < S_) so[col] = p;
      sP[lr * SP_ + col] = f2b((col < S_) ? p : 0.f);
    }
  }
  // zero P pad cols [208,232)
#pragma unroll
  for (int j = 0; j < 6; ++j) {
    int idx = lane + j * 64;
    int pr = idx / 24, pc = idx - pr * 24;
    sP[pr * SP_ + 208 + pc] = 0;
  }
  const unsigned short* Vb = vT + ((size_t)b * D_ + h * HD_) * SPAD;
  f32x4 oacc[4] = {};
#pragma unroll
  for (int ks = 0; ks < 7; ++ks) {
    s16x8 af = *(const s16x8*)(sP + rrow * SP_ + ks * 32 + kk8);
#pragma unroll
    for (int nf = 0; nf < 4; ++nf) {
      s16x8 bfr = *(const s16x8*)(Vb + (size_t)(nf * 16 + rrow) * SPAD + ks * 32 + kk8);
      oacc[nf] = mfma16(af, bfr, oacc[nf]);
    }
  }
#pragma unroll
  for (int r = 0; r < 4; ++r) {
    int row = strip * 16 + rg * 4 + r;
    if (row < S_) {
#pragma unroll
      for (int nf = 0; nf < 4; ++nf) {
        int col = h * HD_ + nf * 16 + rrow;
        attn[(size_t)(b * S_ + row) * D_ + col] = f2b(oacc[nf][r]);
      }
    }
  }
}

// ---------------- classification head ----------------
__global__ __launch_bounds__(256) void head_kernel(const float* __restrict__ cls_ln,
                                                   const float* __restrict__ Wh,
                                                   const float* __restrict__ bh_,
                                                   float* __restrict__ out) {
  int gw = (blockIdx.x * 256 + threadIdx.x) >> 6;
  int lane = threadIdx.x & 63;
  if (gw >= B_ * NCLS_) return;
  int b = gw / NCLS_, c = gw - b * NCLS_;
  const float* x = cls_ln + (size_t)b * D_;
  const float* wr = Wh + (size_t)c * D_;
  float s = 0.f;
  for (int d = lane; d < D_; d += 64) s += x[d] * wr[d];
#pragma unroll
  for (int m = 32; m; m >>= 1) s += __shfl_xor(s, m);
  if (lane == 0) out[(size_t)b * NCLS_ + c] = s + bh_[c];
}

extern "C" void kernel_launch(void* const* d_in, const int* in_sizes, int n_in,
                              void* d_out, int out_size, void* d_ws, size_t ws_size,
                              hipStream_t stream) {
  const float* x     = (const float*)d_in[0];
  const float* Wconv = (const float*)d_in[1];
  const float* bconv = (const float*)d_in[2];
  const float* cls_e = (const float*)d_in[3];
  const float* pos_e = (const float*)d_in[4];
  const float* Wq    = (const float*)d_in[5];
  const float* bq    = (const float*)d_in[6];
  const float* Wk    = (const float*)d_in[7];
  const float* bk    = (const float*)d_in[8];
  const float* Wv    = (const float*)d_in[9];
  const float* bv    = (const float*)d_in[10];
  const float* Wo    = (const float*)d_in[11];
  const float* bo    = (const float*)d_in[12];
  const float* ln1g  = (const float*)d_in[13];
  const float* ln1b  = (const float*)d_in[14];
  const float* Wff1  = (const float*)d_in[15];
  const float* bff1  = (const float*)d_in[16];
  const float* Wff2  = (const float*)d_in[17];
  const float* bff2  = (const float*)d_in[18];
  const float* ln2g  = (const float*)d_in[19];
  const float* ln2b  = (const float*)d_in[20];
  const float* lnfg  = (const float*)d_in[21];
  const float* lnfb  = (const float*)d_in[22];
  const float* Whead = (const float*)d_in[23];
  const float* bhead = (const float*)d_in[24];

  char* base = (char*)d_ws;
  size_t off = 0;
  auto alloc = [&](size_t bytes) {
    void* p = base + off;
    off = (off + bytes + 255) & ~(size_t)255;
    return p;
  };
  unsigned short* Wqkv_b = (unsigned short*)alloc((size_t)L_ * 3 * D_ * D_ * 2);
  unsigned short* Wo_b   = (unsigned short*)alloc((size_t)L_ * D_ * D_ * 2);
  unsigned short* Wff1_b = (unsigned short*)alloc((size_t)L_ * DFF_ * D_ * 2);
  unsigned short* Wff2_b = (unsigned short*)alloc((size_t)L_ * D_ * DFF_ * 2);
  unsigned short* Wconv_b= (unsigned short*)alloc((size_t)D_ * D_ * 2);
  float*          bqkv   = (float*)alloc((size_t)L_ * 2304 * 4);
  float*          h      = (float*)alloc((size_t)MPAD * D_ * 4);
  unsigned short* nbuf   = (unsigned short*)alloc((size_t)MPAD * D_ * 2);
  unsigned short* qbuf   = (unsigned short*)alloc((size_t)MPAD * D_ * 2);
  unsigned short* kbuf   = (unsigned short*)alloc((size_t)MPAD * D_ * 2);
  unsigned short* vbuf   = (unsigned short*)alloc((size_t)MPAD * D_ * 2);
  unsigned short* vT     = (unsigned short*)alloc((size_t)B_ * D_ * SPAD * 2);
  unsigned short* attn   = (unsigned short*)alloc((size_t)MPAD * D_ * 2);
  unsigned short* ff     = (unsigned short*)alloc((size_t)MPAD * DFF_ * 2);
  unsigned short* Xp     = (unsigned short*)alloc((size_t)MPAD * D_ * 2);
  unsigned short* Po     = (unsigned short*)alloc((size_t)2 * MROWS * D_ * 2);
  unsigned short* Pf     = (unsigned short*)alloc((size_t)4 * MROWS * D_ * 2);
  float*          cls_ln = (float*)alloc((size_t)B_ * D_ * 4);
  (void)ws_size; (void)in_sizes; (void)n_in; (void)out_size;

  float* out_f = (float*)d_out;
  float* scores_base = out_f + (size_t)B_ * NCLS_;

  // weight conversions
  cvt_qkv<<<dim3(576, 3, L_), 256, 0, stream>>>(Wq, Wk, Wv, Wqkv_b);
  cvt_bf16<<<2048, 256, 0, stream>>>(Wo,   Wo_b,   (long)L_ * D_ * D_ / 4);
  cvt_bf16<<<2048, 256, 0, stream>>>(Wff1, Wff1_b, (long)L_ * DFF_ * D_ / 4);
  cvt_bf16<<<2048, 256, 0, stream>>>(Wff2, Wff2_b, (long)L_ * D_ * DFF_ / 4);
  cvt_bf16<<<576, 256, 0, stream>>>(Wconv, Wconv_b, (long)D_ * D_ / 4);
  cvt_bias_qkv<<<(L_ * 2304) / 256, 256, 0, stream>>>(bq, bk, bv, bqkv);

  // patch embed (pos folded into epilogue) + cls row init
  im2col<<<(3136 * 768) / 256, 256, 0, stream>>>(x, Xp);
  gemm_bt<3, 1><<<dim3(25, 12), 256, 0, stream>>>(Xp, Wconv_b, bconv, pos_e, h,
                                                  nullptr, nullptr, nullptr, 3136, D_, D_, D_);
  cls_init<<<(B_ * D_ + 255) / 256, 256, 0, stream>>>(h, cls_e, pos_e);
  ln_rows_bf16<<<MROWS, 256, 0, stream>>>(h, ln1g, ln1b, nbuf);

  for (int l = 0; l < L_; ++l) {
    const unsigned short* wqkv = Wqkv_b + (size_t)l * 3 * D_ * D_;
    const unsigned short* wo = Wo_b + (size_t)l * D_ * D_;
    const unsigned short* w1 = Wff1_b + (size_t)l * DFF_ * D_;
    const unsigned short* w2 = Wff2_b + (size_t)l * D_ * DFF_;
    float* sc = scores_base + (size_t)l * BH_ * S_ * S_;

    gemm_bt<5, 1><<<dim3(25, 36), 256, 0, stream>>>(nbuf, wqkv, bqkv + l * 2304, nullptr,
                                                    nullptr, qbuf, kbuf, vbuf, MROWS, 2304, D_, D_);
    transpose_v<<<dim3(B_, 12, 4), 256, 0, stream>>>(vbuf, vT);
    attn_fused<<<dim3(BH_, 13), 64, 0, stream>>>(qbuf, kbuf, vT, sc, attn);
    gemm_bt<6, 2><<<dim3(25, 12, 2), 256, 0, stream>>>(attn, wo, nullptr, nullptr, nullptr,
                                                       Po, nullptr, nullptr, MROWS, D_, D_, D_);
    reduce_ln<2, false><<<MROWS, 256, 0, stream>>>(Po, bo + l * D_, h,
                                                   ln2g + l * D_, ln2b + l * D_, nbuf,
                                                   nullptr, nullptr, nullptr);
    gemm_bt<2, 1><<<dim3(25, 48), 256, 0, stream>>>(nbuf, w1, bff1 + l * DFF_, nullptr,
                                                    nullptr, ff, nullptr, nullptr, MROWS, DFF_, D_, D_);
    gemm_bt<6, 4><<<dim3(25, 12, 4), 256, 0, stream>>>(ff, w2, nullptr, nullptr, nullptr,
                                                       Pf, nullptr, nullptr, MROWS, D_, DFF_, DFF_);
    if (l < L_ - 1) {
      reduce_ln<4, false><<<MROWS, 256, 0, stream>>>(Pf, bff2 + l * D_, h,
                                                     ln1g + (l + 1) * D_, ln1b + (l + 1) * D_, nbuf,
                                                     nullptr, nullptr, nullptr);
    } else {
      reduce_ln<4, true><<<B_, 256, 0, stream>>>(Pf, bff2 + l * D_, h,
                                                 nullptr, nullptr, nullptr,
                                                 lnfg, lnfb, cls_ln);
    }
  }

  head_kernel<<<(B_ * NCLS_ * 64) / 256, 256, 0, stream>>>(cls_ln, Whead, bhead, out_f);
}